// Round 11
// baseline (284.863 us; speedup 1.0000x reference)
//
#include <hip/hip_runtime.h>
#include <hip/hip_bf16.h>

typedef unsigned int u32;
typedef unsigned short u16;
typedef unsigned long long u64;
typedef __bf16 bf16x8 __attribute__((ext_vector_type(8)));
typedef short short8 __attribute__((ext_vector_type(8)));
typedef float floatx4 __attribute__((ext_vector_type(4)));

__device__ inline float b2f(u16 b) { return __uint_as_float((u32)b << 16); }
__device__ inline float lo2f(u32 p) { return __uint_as_float(p << 16); }
__device__ inline float hi2f(u32 p) { return __uint_as_float(p & 0xffff0000u); }
__device__ inline u16 f2bs(float f) {   // RNE f32 -> bf16 bits
    __hip_bfloat16 h = __float2bfloat16(f);
    return *reinterpret_cast<u16*>(&h);
}
// element i of an external float array: f32 (fl=1) or packed bf16 (fl=0)
__device__ inline float ldext(const void* p, int fl, int i) {
    return fl ? ((const float*)p)[i] : b2f(((const u16*)p)[i]);
}

// ---------------------------------------------------------------------------
// flags[0]: edge stride (1 = int64 layout, 0 = int32)
// flags[1]: float inputs are f32 (1) or packed bf16 (0)
// flags[2]: E (edges per timestep), decided by probing data extent
// Also clears bkcnt[512] and the overflow cursor (folded memsets).
__global__ __launch_bounds__(64) void detect_kernel(const int* __restrict__ eb,
                                                    const u32* __restrict__ xw,
                                                    int* __restrict__ flags,
                                                    int* __restrict__ bkcnt,
                                                    int* __restrict__ ovfcur,
                                                    int S, int n) {
    __shared__ int sh[64 * 3];
    int lane = threadIdx.x & 63;
    for (int j = lane; j < 512; j += 64) bkcnt[j] = 0;
    if (lane == 0) *ovfcur = 0;
    int zc = 0, explo = 0;
#pragma unroll
    for (int r = 0; r < 4; ++r) {
        int i = 64 * r + lane;
        zc += (eb[2 * i + 1] == 0) ? 1 : 0;   // int64: odd dwords are hi-words = 0
        u32 w = xw[i];
        int e = (int)((w >> 7) & 0xFF);       // exponent field of LOW half as bf16
        explo += (e >= 96 && e <= 140) ? 1 : 0;
    }
    sh[lane] = zc;
    sh[64 + lane] = explo;
    __syncthreads();
    int fl = 0;
    {
        int z = 0;
        for (int j = 0; j < 64; ++j) z += sh[j];
        fl = (z > 200) ? 1 : 0;   // wave-uniform
    }
    // probe logical indices [S/2, S/2+256): valid node ids => S counts logical
    // elements (E = S/4); garbage => S counts int32 words (E = S/8).
    int vc = 0;
#pragma unroll
    for (int r = 0; r < 4; ++r) {
        int li = S / 2 + 64 * r + lane;
        int v = fl ? eb[2 * li] : eb[li];
        vc += ((unsigned)v < (unsigned)n) ? 1 : 0;
    }
    sh[128 + lane] = vc;
    __syncthreads();
    if (lane == 0) {
        int vtot = 0, etot = 0;
        for (int j = 0; j < 64; ++j) vtot += sh[128 + j];
        for (int j = 0; j < 64; ++j) etot += sh[64 + j];
        flags[0] = fl;
        flags[1] = (etot >= 192) ? 0 : 1;   // bf16-packed signature else f32
        flags[2] = (vtot >= 240) ? (S / 4) : (S / 8);
    }
}

__device__ inline int load_edge(const int* eb, int fl, int idx) {
    return eb[fl ? (idx << 1) : idx];
}

// ---------------------------------------------------------------------------
// CSR build pass 1 (both timesteps): partition edges into global-dst-range
// buckets at FIXED capacity capP (region b*capP, no scan needed). Per-block
// LDS histogram -> one global atomicAdd per bucket -> (g_dst, g_src) u64
// pairs in ~150 B contiguous runs (near-full cache lines). Src stored as
// GLOBAL id t*N+src. Blocks >= gP instead transpose W1,W2 -> bf16 W1t,W2t
// (folded prep_w: saves one dispatch).
#define PCHUNK 4096
__global__ __launch_bounds__(256) void part_kernel(const int* __restrict__ eb,
                                                   const int* __restrict__ flags,
                                                   int* __restrict__ bkcnt,
                                                   u64* __restrict__ pairs,
                                                   int n, int shift, int capP,
                                                   int gP,
                                                   const void* __restrict__ W1,
                                                   const void* __restrict__ W2,
                                                   u16* __restrict__ W1t,
                                                   u16* __restrict__ W2t) {
    __shared__ int cnt[512];
    __shared__ int gbase[512];
    if ((int)blockIdx.x >= gP) {             // prep_w tail blocks
        int tid = (blockIdx.x - gP) * 256 + threadIdx.x;
        if (tid < 2 * 128 * 128) {
            int which = tid >> 14;
            int r = tid & 16383;
            const void* W = which ? W2 : W1;
            u16* Wt = which ? W2t : W1t;
            int c = r >> 7, k = r & 127;
            Wt[c * 128 + k] = f2bs(ldext(W, flags[1], k * 128 + c));
        }
        return;
    }
    const int E = flags[2];
    const int fl = flags[0];
    const int nbuk = (2 * n + (1 << shift) - 1) >> shift;
    const int tid = threadIdx.x;
    for (int i = tid; i < nbuk; i += 256) cnt[i] = 0;
    __syncthreads();
    const int e0 = blockIdx.x * PCHUNK;
    u32 sv[16]; int gv[16], rk[16];
#pragma unroll
    for (int j = 0; j < 16; ++j) {
        int e = e0 + j * 256 + tid;
        u32 gs = 0; int g = -1;
        if (e < 2 * E) {
            int t = (e >= E) ? 1 : 0;
            int le = e - t * E;
            gs = (u32)(t * n) + (u32)load_edge(eb, fl, t * 2 * E + le);
            unsigned du = (unsigned)load_edge(eb, fl, t * 2 * E + E + le);
            if (du < (unsigned)n) g = t * n + (int)du;
        }
        sv[j] = gs;
        gv[j] = g;
        rk[j] = (g >= 0) ? atomicAdd(&cnt[g >> shift], 1) : 0;   // rank in bucket
    }
    __syncthreads();
    for (int b = tid; b < nbuk; b += 256) {
        int c = cnt[b];
        gbase[b] = c ? atomicAdd(&bkcnt[b], c) : 0;              // reserve run
    }
    __syncthreads();
#pragma unroll
    for (int j = 0; j < 16; ++j) {
        if (gv[j] >= 0) {
            int b = gv[j] >> shift;
            int idx = gbase[b] + rk[j];
            if (idx < capP)                                      // overflow guard
                pairs[(size_t)b * capP + idx] =
                    ((u64)(u32)gv[j] << 32) | sv[j];
        }
    }
}

// ---------------------------------------------------------------------------
// CSR build pass 2: one block per bucket. FIXED-32-SLOT layout: node g owns
// ssrc[g*32 .. g*32+32). Values are PRE-CLAMPED to [0, n2] at write time and
// pads are written as n2 (the zero row) — so the gather needs ZERO per-slot
// clamps (round-10 lesson: 32 clamps x 2 VALU were ~25% of gather VALU).
// Rare deg>32 spills to a compact overflow region (also pre-clamped).
__global__ __launch_bounds__(256) void scat_kernel(const u64* __restrict__ pairs,
                                                   const int* __restrict__ bkcnt,
                                                   int* __restrict__ deg,
                                                   float* __restrict__ dinv,
                                                   int* __restrict__ ssrc,
                                                   int* __restrict__ ovf,
                                                   int* __restrict__ ovfoff,
                                                   int* __restrict__ ovfcur,
                                                   int n2, int shift, int capP) {
    __shared__ int hist[1024];
    __shared__ int cur[1024];
    const int b = blockIdx.x;
    const int d0 = b << shift;
    if (d0 >= n2) return;
    int nn = (1 << shift);
    if (d0 + nn > n2) nn = n2 - d0;
    const int tid = threadIdx.x;
    for (int j = tid; j < nn; j += 256) { hist[j] = 0; cur[j] = 0; }
    __syncthreads();
    int cnt = bkcnt[b];
    if (cnt > capP) cnt = capP;
    const u64* pb = pairs + (size_t)b * capP;
    for (int i = tid; i < cnt; i += 256) {
        unsigned dl = (unsigned)(int)(pb[i] >> 32) - (unsigned)d0;
        if (dl < (unsigned)nn) atomicAdd(&hist[dl], 1);
    }
    __syncthreads();
    // degrees -> deg/dinv/overflow alloc; pad slots [deg,32) -> zero row n2
    for (int j = tid; j < nn; j += 256) {
        int d = hist[j];
        int g = d0 + j;
        deg[g] = d;
        dinv[g] = rsqrtf((float)(d + 1));
        if (d > 32) ovfoff[g] = atomicAdd(ovfcur, d - 32);
    }
    for (int idx = tid; idx < nn * 32; idx += 256) {
        int node = idx >> 5, slot = idx & 31;
        if (slot >= hist[node]) ssrc[(size_t)(d0 + node) * 32 + slot] = n2;
    }
    __syncthreads();   // ovfoff visible before scatter reads it
    for (int i = tid; i < cnt; i += 256) {
        u64 p = pb[i];
        unsigned dl = (unsigned)(int)(p >> 32) - (unsigned)d0;
        if (dl < (unsigned)nn) {
            int g = d0 + (int)dl;
            int slot = atomicAdd(&cur[dl], 1);
            u32 v = (u32)p;
            if (v > (u32)n2) v = (u32)n2;    // pre-clamp once per edge
            if (slot < 32) ssrc[(size_t)g * 32 + slot] = (int)v;
            else ovf[ovfoff[g] + slot - 32] = (int)v;
        }
    }
}

// ---------------------------------------------------------------------------
// MFMA GEMM over the unified 2N-row space: hs[g][c] = bf16( dinv[g] * X[g].W )
// mfma_f32_16x16x32_bf16. Block = 4 waves, 64 rows/block; wave = 16 rows x
// 128 cols = 8 col-tiles x 4 K-steps = 32 MFMAs. Wt staged in LDS, row
// stride 136 bf16 (2-way bank aliasing only -> free). Block 0 also zeroes
// the gather pad row at index n (folded memset; runs after scat consumed
// the aliased pairs region, before any gather reads it).
// Verified layouts (learn_hip m89/m91): A[m=lane&15][k=quad*8+j],
// B[n=lane&15][k=quad*8+j], C/D col=lane&15, row=quad*4+reg.
__global__ __launch_bounds__(256) void gemm_mfma(const void* __restrict__ Xv,
                                                 int x_ext,
                                                 const u16* __restrict__ Wt,
                                                 const int* __restrict__ flags,
                                                 const float* __restrict__ dinv,
                                                 u16* __restrict__ hs, int n) {
    if (blockIdx.x == 0 && threadIdx.x < 64)
        ((u32*)hs)[(size_t)n * 64 + threadIdx.x] = 0;   // pad row
    __shared__ u16 Ws[128 * 136];  // Wt[c][k], padded stride 136
    {
        u32* wsu = (u32*)Ws;
        const u32* wtu = (const u32*)Wt;
        for (int i = threadIdx.x; i < 128 * 64; i += 256) {
            int c = i >> 6, kk = i & 63;
            wsu[c * 68 + kk] = wtu[i];
        }
    }
    __syncthreads();

    const int wave = threadIdx.x >> 6;
    const int lane = threadIdx.x & 63;
    const int m = lane & 15;
    const int quad = lane >> 4;
    const int node0 = blockIdx.x * 64 + wave * 16;
    if (node0 >= n) return;

    const int xf32 = x_ext ? flags[1] : 0;   // internal buffers are bf16
    int va = node0 + m;
    if (va > n - 1) va = n - 1;              // clamp; stores guarded

    floatx4 acc[8];
#pragma unroll
    for (int t = 0; t < 8; ++t) acc[t] = (floatx4){0.f, 0.f, 0.f, 0.f};

#pragma unroll
    for (int ks = 0; ks < 4; ++ks) {
        bf16x8 a;
        if (xf32) {
            const float* Xf = (const float*)Xv + (size_t)va * 128 + ks * 32 + quad * 8;
            float4 x0 = *(const float4*)Xf;
            float4 x1 = *(const float4*)(Xf + 4);
            short8 as;
            as[0] = (short)f2bs(x0.x); as[1] = (short)f2bs(x0.y);
            as[2] = (short)f2bs(x0.z); as[3] = (short)f2bs(x0.w);
            as[4] = (short)f2bs(x1.x); as[5] = (short)f2bs(x1.y);
            as[6] = (short)f2bs(x1.z); as[7] = (short)f2bs(x1.w);
            a = __builtin_bit_cast(bf16x8, as);
        } else {
            const u16* Xb = (const u16*)Xv + (size_t)va * 128 + ks * 32 + quad * 8;
            a = *(const bf16x8*)Xb;
        }
#pragma unroll
        for (int t = 0; t < 8; ++t) {
            const bf16x8 b = *(const bf16x8*)(Ws + (16 * t + m) * 136 + ks * 32 + quad * 8);
            acc[t] = __builtin_amdgcn_mfma_f32_16x16x32_bf16(a, b, acc[t], 0, 0, 0);
        }
    }

#pragma unroll
    for (int r = 0; r < 4; ++r) {
        int v = node0 + quad * 4 + r;
        if (v < n) {
            float dv = dinv[v];
#pragma unroll
            for (int t = 0; t < 8; ++t)
                hs[(size_t)v * 128 + 16 * t + m] = f2bs(acc[t][r] * dv);
        }
    }
}

// ---------------------------------------------------------------------------
// out[g] = act( dinv[g] * (hs[g] + sum_{u in in(g)} hs[u]) + bias ), g in [0,2N)
// FIXED-32 gather, clamp-free: ssrc values are pre-clamped by scat (pads =
// zero row n2), so row indices are used RAW — zero per-slot VALU beyond the
// accumulate. Groups 0-1 (slots 0-15) unconditional (index loads stay off the
// deg chain); groups 2/3 guarded by wave-uniform deg tests (P(deg>16)=0.43,
// P(deg>24)=0.02 for Poisson-16) — average row loads 33 -> ~21/wave.
// Row loads keep the full-wave 256 B contiguous pattern (round-5 lesson);
// deep grid (round-7 lesson); no per-element positional checks (round-9
// lesson). Lane owns column pair 2*lane. If imp != null, rows g >= half
// wave-reduce importance = final . Wc + bc.
__global__ __launch_bounds__(256) void gather_kernel(const u16* __restrict__ hs,
                                                     const int* __restrict__ deg,
                                                     const int* __restrict__ ssrc,
                                                     const int* __restrict__ ovf,
                                                     const int* __restrict__ ovfoff,
                                                     const float* __restrict__ dinv,
                                                     const void* __restrict__ bias,
                                                     const int* __restrict__ flags,
                                                     float* __restrict__ outf,
                                                     u16* __restrict__ outb,
                                                     const void* __restrict__ Wc,
                                                     const void* __restrict__ bc,
                                                     float* __restrict__ imp,
                                                     int n2, int half, int relu) {
    const int lane = threadIdx.x & 63;
    int w = __builtin_amdgcn_readfirstlane((blockIdx.x * 256 + threadIdx.x) >> 6);
    if (w >= n2) return;

    const u32* hsu = (const u32*)hs;         // row stride 64 u32
    const int dg = __builtin_amdgcn_readfirstlane(deg[w]);
    const int* sp = ssrc + (size_t)w * 32;   // scalar base, fixed stride

    // slots 0..15: unconditional (no deg dependency)
    int4 q0 = *(const int4*)(sp);
    int4 q1 = *(const int4*)(sp + 4);
    int4 q2 = *(const int4*)(sp + 8);
    int4 q3 = *(const int4*)(sp + 12);
    u32 pself = hsu[(size_t)w * 64 + lane];  // self-loop term

    float ax = lo2f(pself), ay = hi2f(pself);
    float bx = 0.f, by = 0.f, cx = 0.f, cy = 0.f, dx = 0.f, dy = 0.f;

#define ROW(s) hsu[(size_t)(unsigned)(s) * 64 + lane]
    {   // group 0 (slots 0-7)
        u32 v0 = ROW(q0.x), v1 = ROW(q0.y), v2 = ROW(q0.z), v3 = ROW(q0.w);
        u32 v4 = ROW(q1.x), v5 = ROW(q1.y), v6 = ROW(q1.z), v7 = ROW(q1.w);
        ax += lo2f(v0); ay += hi2f(v0);  bx += lo2f(v1); by += hi2f(v1);
        cx += lo2f(v2); cy += hi2f(v2);  dx += lo2f(v3); dy += hi2f(v3);
        ax += lo2f(v4); ay += hi2f(v4);  bx += lo2f(v5); by += hi2f(v5);
        cx += lo2f(v6); cy += hi2f(v6);  dx += lo2f(v7); dy += hi2f(v7);
    }
    {   // group 1 (slots 8-15)
        u32 v0 = ROW(q2.x), v1 = ROW(q2.y), v2 = ROW(q2.z), v3 = ROW(q2.w);
        u32 v4 = ROW(q3.x), v5 = ROW(q3.y), v6 = ROW(q3.z), v7 = ROW(q3.w);
        ax += lo2f(v0); ay += hi2f(v0);  bx += lo2f(v1); by += hi2f(v1);
        cx += lo2f(v2); cy += hi2f(v2);  dx += lo2f(v3); dy += hi2f(v3);
        ax += lo2f(v4); ay += hi2f(v4);  bx += lo2f(v5); by += hi2f(v5);
        cx += lo2f(v6); cy += hi2f(v6);  dx += lo2f(v7); dy += hi2f(v7);
    }
    if (dg > 16) {   // group 2 (slots 16-23), wave-uniform
        int4 q4 = *(const int4*)(sp + 16);
        int4 q5 = *(const int4*)(sp + 20);
        u32 v0 = ROW(q4.x), v1 = ROW(q4.y), v2 = ROW(q4.z), v3 = ROW(q4.w);
        u32 v4 = ROW(q5.x), v5 = ROW(q5.y), v6 = ROW(q5.z), v7 = ROW(q5.w);
        ax += lo2f(v0); ay += hi2f(v0);  bx += lo2f(v1); by += hi2f(v1);
        cx += lo2f(v2); cy += hi2f(v2);  dx += lo2f(v3); dy += hi2f(v3);
        ax += lo2f(v4); ay += hi2f(v4);  bx += lo2f(v5); by += hi2f(v5);
        cx += lo2f(v6); cy += hi2f(v6);  dx += lo2f(v7); dy += hi2f(v7);
    }
    if (dg > 24) {   // group 3 (slots 24-31), wave-uniform
        int4 q6 = *(const int4*)(sp + 24);
        int4 q7 = *(const int4*)(sp + 28);
        u32 v0 = ROW(q6.x), v1 = ROW(q6.y), v2 = ROW(q6.z), v3 = ROW(q6.w);
        u32 v4 = ROW(q7.x), v5 = ROW(q7.y), v6 = ROW(q7.z), v7 = ROW(q7.w);
        ax += lo2f(v0); ay += hi2f(v0);  bx += lo2f(v1); by += hi2f(v1);
        cx += lo2f(v2); cy += hi2f(v2);  dx += lo2f(v3); dy += hi2f(v3);
        ax += lo2f(v4); ay += hi2f(v4);  bx += lo2f(v5); by += hi2f(v5);
        cx += lo2f(v6); cy += hi2f(v6);  dx += lo2f(v7); dy += hi2f(v7);
    }
    if (dg > 32) {   // rare overflow (P ~ 1e-4), wave-uniform branch
        int ob = __builtin_amdgcn_readfirstlane(ovfoff[w]);
        int cnt = dg - 32;
        for (int j = 0; j < cnt; ++j) {
            u32 v = ROW(ovf[ob + j]);        // pre-clamped by scat
            ax += lo2f(v); ay += hi2f(v);
        }
    }
#undef ROW

    ax += bx + cx + dx;
    ay += by + cy + dy;

    const int ffl = flags[1];
    const float dv = dinv[w];
    float o0 = dv * ax + ldext(bias, ffl, 2 * lane);
    float o1 = dv * ay + ldext(bias, ffl, 2 * lane + 1);
    if (relu) {
        o0 = fmaxf(o0, 0.f);
        o1 = fmaxf(o1, 0.f);
    }
    if (outf) ((float2*)outf)[(size_t)w * 64 + lane] = make_float2(o0, o1);
    else ((u32*)outb)[(size_t)w * 64 + lane] = (u32)f2bs(o0) | ((u32)f2bs(o1) << 16);

    if (imp && w >= half) {   // fused importance on final-timestep rows
        float cb = o0 * ldext(Wc, ffl, 2 * lane) + o1 * ldext(Wc, ffl, 2 * lane + 1);
        cb += __shfl_xor(cb, 32);
        cb += __shfl_xor(cb, 16);
        cb += __shfl_xor(cb, 8);
        cb += __shfl_xor(cb, 4);
        cb += __shfl_xor(cb, 2);
        cb += __shfl_xor(cb, 1);
        if (lane == 0) imp[w - half] = cb + ldext(bc, ffl, 0);
    }
}

// ---------------------------------------------------------------------------
extern "C" void kernel_launch(void* const* d_in, const int* in_sizes, int n_in,
                              void* d_out, int out_size, void* d_ws, size_t ws_size,
                              hipStream_t stream) {
    const int T = 2, C = 128;
    const int N = in_sizes[0] / (T * C);   // 50000
    const int S = in_sizes[1];             // edge buffer reported element count
    const int Emax = S / 4;                // upper bound on edges per timestep
    const int N2 = 2 * N;                  // global node space (both timesteps)

    const void* x_seq = d_in[0];
    const int* edges = (const int*)d_in[1];
    const void* W1 = d_in[2];
    const void* b1 = d_in[3];
    const void* W2 = d_in[4];
    const void* b2 = d_in[5];
    const void* Wc = d_in[6];
    const void* bc = d_in[7];

    // d_out is FLOAT32 (reference output dtype): [imp N][h_t0 N*C][h_t1 N*C]
    // R0||R1 is contiguous and g-indexed: row g of the fused layer-2 output.
    float* out = (float*)d_out;
    float* R = out + N;

    // workspace (~75 MB of 256 MB); pairs aliases hsb+hmb (contiguous, dead
    // during CSR build — first GEMM write happens after scat in stream order)
    char* p = (char*)d_ws;
    auto alloc = [&](size_t bytes) {
        char* r = p;
        p += (bytes + 255) & ~(size_t)255;
        return r;
    };
    int* flags = (int*)alloc(256);
    int* deg = (int*)alloc((size_t)N2 * 4);
    float* dinv = (float*)alloc((size_t)N2 * 4);
    int* bkcnt = (int*)alloc(512 * 4);
    int* ovfcur = (int*)alloc(256);
    int* ovfoff = (int*)alloc((size_t)N2 * 4);

    // dst-range bucketing over 2N nodes: <=512 buckets, <=1024 LDS cursors
    int shift = 8;
    while ((((N2 + (1 << shift) - 1) >> shift) > 512) && shift < 10) ++shift;
    const int NBUK = (N2 + (1 << shift) - 1) >> shift;
    // fixed per-bucket pair capacity, sized to the hsb+hmb alias region
    // (~4x the expected per-bucket load for uniform edges)
    const size_t aliasBytes = (size_t)2 * N2 * C * 2;
    const int capP = (int)(aliasBytes / (8 * (size_t)NBUK)) & ~3;

    int* ssrc = (int*)alloc((size_t)N2 * 32 * 4);      // fixed 32 slots/node
    int* ovf = (int*)alloc((size_t)2 * Emax * 4);      // deg>32 spill region
    u16* W1t = (u16*)alloc(128 * 128 * 2);
    u16* W2t = (u16*)alloc(128 * 128 * 2);
    u16* hsb = (u16*)alloc((size_t)(N2 + 2) * C * 2);  // +pad zero row at idx N2
    u16* hmb = (u16*)alloc((size_t)N2 * C * 2);        // bf16 layer-1 activation
    u64* pairs = (u64*)hsb;                            // spans hsb+hmb (contiguous)

    const int gP = (2 * Emax + PCHUNK - 1) / PCHUNK;
    const int gW = (2 * 128 * 128 + 255) / 256;        // prep_w tail blocks
    const int gGA = (N2 + 3) / 4;           // gather: 4 nodes/block (1/wave)
    const int gG2 = (N2 + 63) / 64;         // mfma gemm: block per 64 rows

    detect_kernel<<<1, 64, 0, stream>>>(edges, (const u32*)x_seq, flags, bkcnt,
                                        ovfcur, S, N);

    // --- CSR build (both timesteps) + weight prep in one dispatch ---
    part_kernel<<<gP + gW, 256, 0, stream>>>(edges, flags, bkcnt, pairs, N, shift,
                                             capP, gP, W1, W2, W1t, W2t);
    scat_kernel<<<NBUK, 256, 0, stream>>>(pairs, bkcnt, deg, dinv, ssrc,
                                          ovf, ovfoff, ovfcur, N2, shift, capP);

    // --- layer 1 over all 2N rows: hsb = dinv*(X @ W1); hmb = relu(gather)+b1 ---
    gemm_mfma<<<gG2, 256, 0, stream>>>(x_seq, 1, W1t, flags, dinv, hsb, N2);
    gather_kernel<<<gGA, 256, 0, stream>>>(hsb, deg, ssrc, ovf, ovfoff, dinv, b1,
                                           flags, (float*)nullptr, hmb,
                                           nullptr, nullptr, (float*)nullptr,
                                           N2, N, 1);

    // --- layer 2 over all 2N rows: hsb = dinv*(hmb @ W2); R = gather + b2 ---
    gemm_mfma<<<gG2, 256, 0, stream>>>(hmb, 0, W2t, flags, dinv, hsb, N2);
    gather_kernel<<<gGA, 256, 0, stream>>>(hsb, deg, ssrc, ovf, ovfoff, dinv, b2,
                                           flags, R, (u16*)nullptr,
                                           Wc, bc, out,
                                           N2, N, 0);
}

// Round 12
// 284.379 us; speedup vs baseline: 1.0017x; 1.0017x over previous
//
#include <hip/hip_runtime.h>
#include <hip/hip_bf16.h>

typedef unsigned int u32;
typedef unsigned short u16;
typedef unsigned long long u64;
typedef __bf16 bf16x8 __attribute__((ext_vector_type(8)));
typedef short short8 __attribute__((ext_vector_type(8)));
typedef float floatx4 __attribute__((ext_vector_type(4)));

__device__ inline float b2f(u16 b) { return __uint_as_float((u32)b << 16); }
__device__ inline float lo2f(u32 p) { return __uint_as_float(p << 16); }
__device__ inline float hi2f(u32 p) { return __uint_as_float(p & 0xffff0000u); }
__device__ inline u16 f2bs(float f) {   // RNE f32 -> bf16 bits
    __hip_bfloat16 h = __float2bfloat16(f);
    return *reinterpret_cast<u16*>(&h);
}
// element i of an external float array: f32 (fl=1) or packed bf16 (fl=0)
__device__ inline float ldext(const void* p, int fl, int i) {
    return fl ? ((const float*)p)[i] : b2f(((const u16*)p)[i]);
}

// ---------------------------------------------------------------------------
// Block 0: flags probe (edge stride / float dtype / E) + clears bkcnt, ovfcur,
// dinv[n2]=0 (pad-row scale; pads contribute exact +0.0 in the gather).
// Blocks 1..: W1,W2 -> bf16 transposed W1t,W2t. They SELF-probe the dtype
// (re-derive fl1 from xw exponents) so there is no intra-dispatch flags race.
__global__ __launch_bounds__(256) void detect_kernel(const int* __restrict__ eb,
                                                     const u32* __restrict__ xw,
                                                     int* __restrict__ flags,
                                                     int* __restrict__ bkcnt,
                                                     int* __restrict__ ovfcur,
                                                     float* __restrict__ dinv,
                                                     const void* __restrict__ W1,
                                                     const void* __restrict__ W2,
                                                     u16* __restrict__ W1t,
                                                     u16* __restrict__ W2t,
                                                     int S, int n, int n2) {
    __shared__ int sh[512];
    __shared__ int res[2];
    const int tid = threadIdx.x;
    u32 wx = xw[tid];
    int e = (int)((wx >> 7) & 0xFF);          // exponent of LOW half as bf16
    int explo = (e >= 96 && e <= 140) ? 1 : 0;

    if (blockIdx.x > 0) {                     // ---- W-prep tail blocks ----
        sh[tid] = explo;
        __syncthreads();
        for (int o = 128; o > 0; o >>= 1) {
            if (tid < o) sh[tid] += sh[tid + o];
            __syncthreads();
        }
        int fl1 = (sh[0] >= 192) ? 0 : 1;     // bf16-packed signature else f32
        int t2 = ((int)blockIdx.x - 1) * 256 + tid;
        if (t2 < 2 * 128 * 128) {
            int which = t2 >> 14, r = t2 & 16383;
            const void* W = which ? W2 : W1;
            u16* Wt = which ? W2t : W1t;
            int c = r >> 7, k = r & 127;
            Wt[c * 128 + k] = f2bs(ldext(W, fl1, k * 128 + c));
        }
        return;
    }

    // ---- block 0: full probe ----
    for (int j = tid; j < 512; j += 256) bkcnt[j] = 0;
    if (tid == 0) { *ovfcur = 0; dinv[n2] = 0.0f; }
    sh[tid] = (eb[2 * tid + 1] == 0) ? 1 : 0; // int64: odd dwords = hi words = 0
    sh[256 + tid] = explo;
    __syncthreads();
    if (tid == 0) {
        int z = 0, et = 0;
        for (int j = 0; j < 256; ++j) { z += sh[j]; et += sh[256 + j]; }
        res[0] = (z > 200) ? 1 : 0;
        res[1] = et;
    }
    __syncthreads();
    int fl = res[0];
    // probe logical indices [S/2, S/2+256): valid node ids => S counts logical
    // elements (E = S/4); garbage => S counts int32 words (E = S/8).
    int li = S / 2 + tid;
    int v = fl ? eb[2 * li] : eb[li];
    sh[tid] = ((unsigned)v < (unsigned)n) ? 1 : 0;
    __syncthreads();
    if (tid == 0) {
        int vt = 0;
        for (int j = 0; j < 256; ++j) vt += sh[j];
        flags[0] = fl;
        flags[1] = (res[1] >= 192) ? 0 : 1;
        flags[2] = (vt >= 240) ? (S / 4) : (S / 8);
    }
}

__device__ inline int load_edge(const int* eb, int fl, int idx) {
    return eb[fl ? (idx << 1) : idx];
}

// ---------------------------------------------------------------------------
// COMBINED dispatch: blocks < gP partition edges into global-dst-range buckets
// (fixed capacity capP, LDS histogram, one global atomicAdd per bucket, u64
// (g_dst,g_src) pairs in ~150 B runs). Blocks >= gP run layer-1 MFMA GEMM over
// the unified 2N-row space, storing UNSCALED bf16 rows (dinv is applied at
// gather time — identical relative rounding error, and it breaks the
// scat->gemm dependency so part and gemm1 overlap in one dispatch).
// pairs no longer aliases hsb (gemm writes hsb concurrently).
#define PCHUNK 4096
__global__ __launch_bounds__(256) void part_gemm(const int* __restrict__ eb,
                                                 const int* __restrict__ flags,
                                                 int* __restrict__ bkcnt,
                                                 u64* __restrict__ pairs,
                                                 int n, int shift, int capP,
                                                 int gP,
                                                 const void* __restrict__ Xv,
                                                 const u16* __restrict__ W1t,
                                                 u16* __restrict__ hs, int nrows) {
    __shared__ int cnt[512];
    __shared__ int gbase[512];
    __shared__ u16 Ws[128 * 136];            // Wt[c][k], padded stride 136

    if ((int)blockIdx.x >= gP) {             // ---------- gemm1 tail ----------
        const int gb = blockIdx.x - gP;
        if (gb == 0 && threadIdx.x < 64)
            ((u32*)hs)[(size_t)nrows * 64 + threadIdx.x] = 0;   // pad row
        {
            u32* wsu = (u32*)Ws;
            const u32* wtu = (const u32*)W1t;
            for (int i = threadIdx.x; i < 128 * 64; i += 256) {
                int c = i >> 6, kk = i & 63;
                wsu[c * 68 + kk] = wtu[i];
            }
        }
        __syncthreads();
        const int wave = threadIdx.x >> 6;
        const int lane = threadIdx.x & 63;
        const int m = lane & 15;
        const int quad = lane >> 4;
        const int node0 = gb * 64 + wave * 16;
        if (node0 >= nrows) return;
        const int xf32 = flags[1];           // external X dtype
        int va = node0 + m;
        if (va > nrows - 1) va = nrows - 1;  // clamp; stores guarded
        floatx4 acc[8];
#pragma unroll
        for (int t = 0; t < 8; ++t) acc[t] = (floatx4){0.f, 0.f, 0.f, 0.f};
#pragma unroll
        for (int ks = 0; ks < 4; ++ks) {
            bf16x8 a;
            if (xf32) {
                const float* Xf = (const float*)Xv + (size_t)va * 128 + ks * 32 + quad * 8;
                float4 x0 = *(const float4*)Xf;
                float4 x1 = *(const float4*)(Xf + 4);
                short8 as;
                as[0] = (short)f2bs(x0.x); as[1] = (short)f2bs(x0.y);
                as[2] = (short)f2bs(x0.z); as[3] = (short)f2bs(x0.w);
                as[4] = (short)f2bs(x1.x); as[5] = (short)f2bs(x1.y);
                as[6] = (short)f2bs(x1.z); as[7] = (short)f2bs(x1.w);
                a = __builtin_bit_cast(bf16x8, as);
            } else {
                const u16* Xb = (const u16*)Xv + (size_t)va * 128 + ks * 32 + quad * 8;
                a = *(const bf16x8*)Xb;
            }
#pragma unroll
            for (int t = 0; t < 8; ++t) {
                const bf16x8 b = *(const bf16x8*)(Ws + (16 * t + m) * 136 + ks * 32 + quad * 8);
                acc[t] = __builtin_amdgcn_mfma_f32_16x16x32_bf16(a, b, acc[t], 0, 0, 0);
            }
        }
#pragma unroll
        for (int r = 0; r < 4; ++r) {
            int vv = node0 + quad * 4 + r;
            if (vv < nrows) {
#pragma unroll
                for (int t = 0; t < 8; ++t)
                    hs[(size_t)vv * 128 + 16 * t + m] = f2bs(acc[t][r]);   // UNSCALED
            }
        }
        return;
    }

    // ---------- part body ----------
    const int E = flags[2];
    const int fl = flags[0];
    const int nbuk = (2 * n + (1 << shift) - 1) >> shift;
    const int tid = threadIdx.x;
    for (int i = tid; i < nbuk; i += 256) cnt[i] = 0;
    __syncthreads();
    const int e0 = blockIdx.x * PCHUNK;
    u32 sv[16]; int gv[16], rk[16];
#pragma unroll
    for (int j = 0; j < 16; ++j) {
        int e = e0 + j * 256 + tid;
        u32 gs = 0; int g = -1;
        if (e < 2 * E) {
            int t = (e >= E) ? 1 : 0;
            int le = e - t * E;
            gs = (u32)(t * n) + (u32)load_edge(eb, fl, t * 2 * E + le);
            unsigned du = (unsigned)load_edge(eb, fl, t * 2 * E + E + le);
            if (du < (unsigned)n) g = t * n + (int)du;
        }
        sv[j] = gs;
        gv[j] = g;
        rk[j] = (g >= 0) ? atomicAdd(&cnt[g >> shift], 1) : 0;   // rank in bucket
    }
    __syncthreads();
    for (int b = tid; b < nbuk; b += 256) {
        int c = cnt[b];
        gbase[b] = c ? atomicAdd(&bkcnt[b], c) : 0;              // reserve run
    }
    __syncthreads();
#pragma unroll
    for (int j = 0; j < 16; ++j) {
        if (gv[j] >= 0) {
            int b = gv[j] >> shift;
            int idx = gbase[b] + rk[j];
            if (idx < capP)                                      // overflow guard
                pairs[(size_t)b * capP + idx] =
                    ((u64)(u32)gv[j] << 32) | sv[j];
        }
    }
}

// ---------------------------------------------------------------------------
// CSR build pass 2: one block per bucket. FIXED-32-SLOT layout: node g owns
// ssrc[g*32 .. g*32+32). Values PRE-CLAMPED to [0, n2]; pads written as n2
// (zero row, dinv[n2]=0 -> exact +0.0 in the gather). Rare deg>32 spills to
// a compact overflow region. LDS histogram gives degrees; deg/dinv coalesced.
__global__ __launch_bounds__(256) void scat_kernel(const u64* __restrict__ pairs,
                                                   const int* __restrict__ bkcnt,
                                                   int* __restrict__ deg,
                                                   float* __restrict__ dinv,
                                                   int* __restrict__ ssrc,
                                                   int* __restrict__ ovf,
                                                   int* __restrict__ ovfoff,
                                                   int* __restrict__ ovfcur,
                                                   int n2, int shift, int capP) {
    __shared__ int hist[1024];
    __shared__ int cur[1024];
    const int b = blockIdx.x;
    const int d0 = b << shift;
    if (d0 >= n2) return;
    int nn = (1 << shift);
    if (d0 + nn > n2) nn = n2 - d0;
    const int tid = threadIdx.x;
    for (int j = tid; j < nn; j += 256) { hist[j] = 0; cur[j] = 0; }
    __syncthreads();
    int cnt = bkcnt[b];
    if (cnt > capP) cnt = capP;
    const u64* pb = pairs + (size_t)b * capP;
    for (int i = tid; i < cnt; i += 256) {
        unsigned dl = (unsigned)(int)(pb[i] >> 32) - (unsigned)d0;
        if (dl < (unsigned)nn) atomicAdd(&hist[dl], 1);
    }
    __syncthreads();
    for (int j = tid; j < nn; j += 256) {
        int d = hist[j];
        int g = d0 + j;
        deg[g] = d;
        dinv[g] = rsqrtf((float)(d + 1));
        if (d > 32) ovfoff[g] = atomicAdd(ovfcur, d - 32);
    }
    for (int idx = tid; idx < nn * 32; idx += 256) {
        int node = idx >> 5, slot = idx & 31;
        if (slot >= hist[node]) ssrc[(size_t)(d0 + node) * 32 + slot] = n2;
    }
    __syncthreads();   // ovfoff visible before scatter reads it
    for (int i = tid; i < cnt; i += 256) {
        u64 p = pb[i];
        unsigned dl = (unsigned)(int)(p >> 32) - (unsigned)d0;
        if (dl < (unsigned)nn) {
            int g = d0 + (int)dl;
            int slot = atomicAdd(&cur[dl], 1);
            u32 v = (u32)p;
            if (v > (u32)n2) v = (u32)n2;    // pre-clamp once per edge
            if (slot < 32) ssrc[(size_t)g * 32 + slot] = (int)v;
            else ovf[ovfoff[g] + slot - 32] = (int)v;
        }
    }
}

// ---------------------------------------------------------------------------
// Standalone layer-2 GEMM (input hmb bf16), UNSCALED output like gemm1.
__global__ __launch_bounds__(256) void gemm_mfma(const u16* __restrict__ Xb0,
                                                 const u16* __restrict__ Wt,
                                                 u16* __restrict__ hs, int nrows) {
    if (blockIdx.x == 0 && threadIdx.x < 64)
        ((u32*)hs)[(size_t)nrows * 64 + threadIdx.x] = 0;   // pad row
    __shared__ u16 Ws[128 * 136];
    {
        u32* wsu = (u32*)Ws;
        const u32* wtu = (const u32*)Wt;
        for (int i = threadIdx.x; i < 128 * 64; i += 256) {
            int c = i >> 6, kk = i & 63;
            wsu[c * 68 + kk] = wtu[i];
        }
    }
    __syncthreads();
    const int wave = threadIdx.x >> 6;
    const int lane = threadIdx.x & 63;
    const int m = lane & 15;
    const int quad = lane >> 4;
    const int node0 = blockIdx.x * 64 + wave * 16;
    if (node0 >= nrows) return;
    int va = node0 + m;
    if (va > nrows - 1) va = nrows - 1;
    floatx4 acc[8];
#pragma unroll
    for (int t = 0; t < 8; ++t) acc[t] = (floatx4){0.f, 0.f, 0.f, 0.f};
#pragma unroll
    for (int ks = 0; ks < 4; ++ks) {
        const u16* Xb = Xb0 + (size_t)va * 128 + ks * 32 + quad * 8;
        bf16x8 a = *(const bf16x8*)Xb;
#pragma unroll
        for (int t = 0; t < 8; ++t) {
            const bf16x8 b = *(const bf16x8*)(Ws + (16 * t + m) * 136 + ks * 32 + quad * 8);
            acc[t] = __builtin_amdgcn_mfma_f32_16x16x32_bf16(a, b, acc[t], 0, 0, 0);
        }
    }
#pragma unroll
    for (int r = 0; r < 4; ++r) {
        int vv = node0 + quad * 4 + r;
        if (vv < nrows) {
#pragma unroll
            for (int t = 0; t < 8; ++t)
                hs[(size_t)vv * 128 + 16 * t + m] = f2bs(acc[t][r]);   // UNSCALED
        }
    }
}

// ---------------------------------------------------------------------------
// out[g] = act( dinv[g]*( dinv[g]*hs[g] + sum_u dinv[u]*hs[u] ) + bias )
// FIXED-32 gather; hs rows are UNSCALED so each gathered row is weighted by
// dinv[src] (wave-uniform broadcast load, L2-hot 400 KB array; fma replaces
// add at equal VALU rate — round-11 showed VALU is free). Pads: row n2 is
// zero AND dinv[n2]=0 -> exact +0.0. Groups 0-1 unconditional; groups 2/3
// wave-uniform deg-gated. Full-wave 256 B row loads (round-5 lesson), deep
// grid (round-7), no positional checks (round-9), no per-slot clamps
// (round-10/11: pre-clamped by scat).
__global__ __launch_bounds__(256) void gather_kernel(const u16* __restrict__ hs,
                                                     const int* __restrict__ deg,
                                                     const int* __restrict__ ssrc,
                                                     const int* __restrict__ ovf,
                                                     const int* __restrict__ ovfoff,
                                                     const float* __restrict__ dinv,
                                                     const void* __restrict__ bias,
                                                     const int* __restrict__ flags,
                                                     float* __restrict__ outf,
                                                     u16* __restrict__ outb,
                                                     const void* __restrict__ Wc,
                                                     const void* __restrict__ bc,
                                                     float* __restrict__ imp,
                                                     int n2, int half, int relu) {
    const int lane = threadIdx.x & 63;
    int w = __builtin_amdgcn_readfirstlane((blockIdx.x * 256 + threadIdx.x) >> 6);
    if (w >= n2) return;

    const u32* hsu = (const u32*)hs;         // row stride 64 u32
    const int dg = __builtin_amdgcn_readfirstlane(deg[w]);
    const int* sp = ssrc + (size_t)w * 32;   // scalar base, fixed stride
    const float dvw = dinv[w];

    int4 q0 = *(const int4*)(sp);
    int4 q1 = *(const int4*)(sp + 4);
    int4 q2 = *(const int4*)(sp + 8);
    int4 q3 = *(const int4*)(sp + 12);
    u32 pself = hsu[(size_t)w * 64 + lane];  // self-loop term

    float ax = dvw * lo2f(pself), ay = dvw * hi2f(pself);
    float bx = 0.f, by = 0.f, cx = 0.f, cy = 0.f, dx = 0.f, dy = 0.f;

#define ROW(s) hsu[(size_t)(unsigned)(s) * 64 + lane]
#define DV(s) dinv[(unsigned)(s)]
    {   // group 0 (slots 0-7)
        float d0 = DV(q0.x), d1 = DV(q0.y), d2 = DV(q0.z), d3 = DV(q0.w);
        float d4 = DV(q1.x), d5 = DV(q1.y), d6 = DV(q1.z), d7 = DV(q1.w);
        u32 v0 = ROW(q0.x), v1 = ROW(q0.y), v2 = ROW(q0.z), v3 = ROW(q0.w);
        u32 v4 = ROW(q1.x), v5 = ROW(q1.y), v6 = ROW(q1.z), v7 = ROW(q1.w);
        ax += d0 * lo2f(v0); ay += d0 * hi2f(v0);  bx += d1 * lo2f(v1); by += d1 * hi2f(v1);
        cx += d2 * lo2f(v2); cy += d2 * hi2f(v2);  dx += d3 * lo2f(v3); dy += d3 * hi2f(v3);
        ax += d4 * lo2f(v4); ay += d4 * hi2f(v4);  bx += d5 * lo2f(v5); by += d5 * hi2f(v5);
        cx += d6 * lo2f(v6); cy += d6 * hi2f(v6);  dx += d7 * lo2f(v7); dy += d7 * hi2f(v7);
    }
    {   // group 1 (slots 8-15)
        float d0 = DV(q2.x), d1 = DV(q2.y), d2 = DV(q2.z), d3 = DV(q2.w);
        float d4 = DV(q3.x), d5 = DV(q3.y), d6 = DV(q3.z), d7 = DV(q3.w);
        u32 v0 = ROW(q2.x), v1 = ROW(q2.y), v2 = ROW(q2.z), v3 = ROW(q2.w);
        u32 v4 = ROW(q3.x), v5 = ROW(q3.y), v6 = ROW(q3.z), v7 = ROW(q3.w);
        ax += d0 * lo2f(v0); ay += d0 * hi2f(v0);  bx += d1 * lo2f(v1); by += d1 * hi2f(v1);
        cx += d2 * lo2f(v2); cy += d2 * hi2f(v2);  dx += d3 * lo2f(v3); dy += d3 * hi2f(v3);
        ax += d4 * lo2f(v4); ay += d4 * hi2f(v4);  bx += d5 * lo2f(v5); by += d5 * hi2f(v5);
        cx += d6 * lo2f(v6); cy += d6 * hi2f(v6);  dx += d7 * lo2f(v7); dy += d7 * hi2f(v7);
    }
    if (dg > 16) {   // group 2 (slots 16-23), wave-uniform
        int4 q4 = *(const int4*)(sp + 16);
        int4 q5 = *(const int4*)(sp + 20);
        float d0 = DV(q4.x), d1 = DV(q4.y), d2 = DV(q4.z), d3 = DV(q4.w);
        float d4 = DV(q5.x), d5 = DV(q5.y), d6 = DV(q5.z), d7 = DV(q5.w);
        u32 v0 = ROW(q4.x), v1 = ROW(q4.y), v2 = ROW(q4.z), v3 = ROW(q4.w);
        u32 v4 = ROW(q5.x), v5 = ROW(q5.y), v6 = ROW(q5.z), v7 = ROW(q5.w);
        ax += d0 * lo2f(v0); ay += d0 * hi2f(v0);  bx += d1 * lo2f(v1); by += d1 * hi2f(v1);
        cx += d2 * lo2f(v2); cy += d2 * hi2f(v2);  dx += d3 * lo2f(v3); dy += d3 * hi2f(v3);
        ax += d4 * lo2f(v4); ay += d4 * hi2f(v4);  bx += d5 * lo2f(v5); by += d5 * hi2f(v5);
        cx += d6 * lo2f(v6); cy += d6 * hi2f(v6);  dx += d7 * lo2f(v7); dy += d7 * hi2f(v7);
    }
    if (dg > 24) {   // group 3 (slots 24-31), wave-uniform
        int4 q6 = *(const int4*)(sp + 24);
        int4 q7 = *(const int4*)(sp + 28);
        float d0 = DV(q6.x), d1 = DV(q6.y), d2 = DV(q6.z), d3 = DV(q6.w);
        float d4 = DV(q7.x), d5 = DV(q7.y), d6 = DV(q7.z), d7 = DV(q7.w);
        u32 v0 = ROW(q6.x), v1 = ROW(q6.y), v2 = ROW(q6.z), v3 = ROW(q6.w);
        u32 v4 = ROW(q7.x), v5 = ROW(q7.y), v6 = ROW(q7.z), v7 = ROW(q7.w);
        ax += d0 * lo2f(v0); ay += d0 * hi2f(v0);  bx += d1 * lo2f(v1); by += d1 * hi2f(v1);
        cx += d2 * lo2f(v2); cy += d2 * hi2f(v2);  dx += d3 * lo2f(v3); dy += d3 * hi2f(v3);
        ax += d4 * lo2f(v4); ay += d4 * hi2f(v4);  bx += d5 * lo2f(v5); by += d5 * hi2f(v5);
        cx += d6 * lo2f(v6); cy += d6 * hi2f(v6);  dx += d7 * lo2f(v7); dy += d7 * hi2f(v7);
    }
    if (dg > 32) {   // rare overflow (P ~ 1e-4), wave-uniform branch
        int ob = __builtin_amdgcn_readfirstlane(ovfoff[w]);
        int cnt = dg - 32;
        for (int j = 0; j < cnt; ++j) {
            int s = ovf[ob + j];             // pre-clamped by scat
            float dd = DV(s);
            u32 v = ROW(s);
            ax += dd * lo2f(v); ay += dd * hi2f(v);
        }
    }
#undef ROW
#undef DV

    ax += bx + cx + dx;
    ay += by + cy + dy;

    const int ffl = flags[1];
    float o0 = dvw * ax + ldext(bias, ffl, 2 * lane);
    float o1 = dvw * ay + ldext(bias, ffl, 2 * lane + 1);
    if (relu) {
        o0 = fmaxf(o0, 0.f);
        o1 = fmaxf(o1, 0.f);
    }
    if (outf) ((float2*)outf)[(size_t)w * 64 + lane] = make_float2(o0, o1);
    else ((u32*)outb)[(size_t)w * 64 + lane] = (u32)f2bs(o0) | ((u32)f2bs(o1) << 16);

    if (imp && w >= half) {   // fused importance on final-timestep rows
        float cb = o0 * ldext(Wc, ffl, 2 * lane) + o1 * ldext(Wc, ffl, 2 * lane + 1);
        cb += __shfl_xor(cb, 32);
        cb += __shfl_xor(cb, 16);
        cb += __shfl_xor(cb, 8);
        cb += __shfl_xor(cb, 4);
        cb += __shfl_xor(cb, 2);
        cb += __shfl_xor(cb, 1);
        if (lane == 0) imp[w - half] = cb + ldext(bc, ffl, 0);
    }
}

// ---------------------------------------------------------------------------
extern "C" void kernel_launch(void* const* d_in, const int* in_sizes, int n_in,
                              void* d_out, int out_size, void* d_ws, size_t ws_size,
                              hipStream_t stream) {
    const int T = 2, C = 128;
    const int N = in_sizes[0] / (T * C);   // 50000
    const int S = in_sizes[1];             // edge buffer reported element count
    const int Emax = S / 4;                // upper bound on edges per timestep
    const int N2 = 2 * N;                  // global node space (both timesteps)

    const void* x_seq = d_in[0];
    const int* edges = (const int*)d_in[1];
    const void* W1 = d_in[2];
    const void* b1 = d_in[3];
    const void* W2 = d_in[4];
    const void* b2 = d_in[5];
    const void* Wc = d_in[6];
    const void* bc = d_in[7];

    // d_out is FLOAT32 (reference output dtype): [imp N][h_t0 N*C][h_t1 N*C]
    float* out = (float*)d_out;
    float* R = out + N;

    // workspace (~130 MB of 256 MB); pairs is now its OWN buffer (gemm1 writes
    // hsb concurrently with part writing pairs in the combined dispatch)
    char* p = (char*)d_ws;
    auto alloc = [&](size_t bytes) {
        char* r = p;
        p += (bytes + 255) & ~(size_t)255;
        return r;
    };
    int* flags = (int*)alloc(256);
    int* deg = (int*)alloc((size_t)N2 * 4);
    float* dinv = (float*)alloc((size_t)(N2 + 1) * 4);   // +1: dinv[N2]=0 (pad)
    int* bkcnt = (int*)alloc(512 * 4);
    int* ovfcur = (int*)alloc(256);
    int* ovfoff = (int*)alloc((size_t)N2 * 4);

    // dst-range bucketing over 2N nodes: <=512 buckets, <=1024 LDS cursors
    int shift = 8;
    while ((((N2 + (1 << shift) - 1) >> shift) > 512) && shift < 10) ++shift;
    const int NBUK = (N2 + (1 << shift) - 1) >> shift;
    const size_t pairBytes = (size_t)2 * N2 * C * 2;     // same capacity as before
    const int capP = (int)(pairBytes / (8 * (size_t)NBUK)) & ~3;

    int* ssrc = (int*)alloc((size_t)N2 * 32 * 4);        // fixed 32 slots/node
    int* ovf = (int*)alloc((size_t)2 * Emax * 4);        // deg>32 spill region
    u16* W1t = (u16*)alloc(128 * 128 * 2);
    u16* W2t = (u16*)alloc(128 * 128 * 2);
    u16* hsb = (u16*)alloc((size_t)(N2 + 2) * C * 2);    // +pad zero row at N2
    u16* hmb = (u16*)alloc((size_t)N2 * C * 2);          // bf16 layer-1 activation
    u64* pairs = (u64*)alloc((size_t)NBUK * capP * 8);   // dedicated buffer

    const int gP = (2 * Emax + PCHUNK - 1) / PCHUNK;
    const int gW = (2 * 128 * 128 + 255) / 256;          // W-prep tail blocks
    const int gGA = (N2 + 3) / 4;           // gather: 4 nodes/block (1/wave)
    const int gG2 = (N2 + 63) / 64;         // mfma gemm: block per 64 rows

    // D1: probe + W-prep (self-probing tails, no flags race)
    detect_kernel<<<1 + gW, 256, 0, stream>>>(edges, (const u32*)x_seq, flags,
                                              bkcnt, ovfcur, dinv,
                                              W1, W2, W1t, W2t, S, N, N2);
    // D2: CSR partition (both timesteps) OVERLAPPED with layer-1 GEMM
    part_gemm<<<gP + gG2, 256, 0, stream>>>(edges, flags, bkcnt, pairs, N, shift,
                                            capP, gP, x_seq, W1t, hsb, N2);
    // D3: bucket scatter -> fixed-32 ssrc + deg/dinv
    scat_kernel<<<NBUK, 256, 0, stream>>>(pairs, bkcnt, deg, dinv, ssrc,
                                          ovf, ovfoff, ovfcur, N2, shift, capP);
    // D4: layer-1 aggregate (+relu+b1), applies dinv at gather time
    gather_kernel<<<gGA, 256, 0, stream>>>(hsb, deg, ssrc, ovf, ovfoff, dinv, b1,
                                           flags, (float*)nullptr, hmb,
                                           nullptr, nullptr, (float*)nullptr,
                                           N2, N, 1);
    // D5: layer-2 GEMM (unscaled)
    gemm_mfma<<<gG2, 256, 0, stream>>>(hmb, W2t, hsb, N2);
    // D6: layer-2 aggregate + b2 -> R (f32), fused importance
    gather_kernel<<<gGA, 256, 0, stream>>>(hsb, deg, ssrc, ovf, ovfoff, dinv, b2,
                                           flags, R, (u16*)nullptr,
                                           Wc, bc, out,
                                           N2, N, 0);
}